// Round 4
// baseline (82.242 us; speedup 1.0000x reference)
//
#include <hip/hip_runtime.h>
#include <stdint.h>

// ---------------- Threefry-2x32, 20 rounds (exactly JAX's) ----------------
__host__ __device__ inline void tf2x32(uint32_t k0, uint32_t k1,
                                       uint32_t x0, uint32_t x1,
                                       uint32_t& o0, uint32_t& o1) {
  uint32_t k2 = k0 ^ k1 ^ 0x1BD11BDAu;
#define TFR(r) { x0 += x1; x1 = (x1 << (r)) | (x1 >> (32 - (r))); x1 ^= x0; }
  x0 += k0; x1 += k1;
  TFR(13) TFR(15) TFR(26) TFR(6)  x0 += k1; x1 += k2 + 1u;
  TFR(17) TFR(29) TFR(16) TFR(24) x0 += k2; x1 += k0 + 2u;
  TFR(13) TFR(15) TFR(26) TFR(6)  x0 += k0; x1 += k1 + 3u;
  TFR(17) TFR(29) TFR(16) TFR(24) x0 += k1; x1 += k2 + 4u;
  TFR(13) TFR(15) TFR(26) TFR(6)  x0 += k2; x1 += k0 + 5u;
#undef TFR
  o0 = x0; o1 = x1;
}

// 4-chain lockstep threefry: counter hi = 0, lo = j[i]; out = o0^o1 (JAX
// partitionable random_bits). Manual interleave => dep distance 4.
__device__ __forceinline__ void tf4(uint32_t k0, uint32_t k1,
                                    const uint32_t j[4], uint32_t out[4]) {
  uint32_t k2 = k0 ^ k1 ^ 0x1BD11BDAu;
  uint32_t a[4], b[4];
#pragma unroll
  for (int i = 0; i < 4; ++i) { a[i] = k0; b[i] = j[i] + k1; }
#define RND(r)                                                         \
  _Pragma("unroll") for (int i = 0; i < 4; ++i) {                      \
    a[i] += b[i];                                                      \
    b[i] = (b[i] << (r)) | (b[i] >> (32 - (r)));                       \
    b[i] ^= a[i];                                                      \
  }
#define INJ(ka, kb, n)                                                 \
  _Pragma("unroll") for (int i = 0; i < 4; ++i) {                      \
    a[i] += (ka); b[i] += (kb) + (n);                                  \
  }
  RND(13) RND(15) RND(26) RND(6)  INJ(k1, k2, 1u)
  RND(17) RND(29) RND(16) RND(24) INJ(k2, k0, 2u)
  RND(13) RND(15) RND(26) RND(6)  INJ(k0, k1, 3u)
  RND(17) RND(29) RND(16) RND(24) INJ(k1, k2, 4u)
  RND(13) RND(15) RND(26) RND(6)  INJ(k2, k0, 5u)
#undef RND
#undef INJ
#pragma unroll
  for (int i = 0; i < 4; ++i) out[i] = a[i] ^ b[i];
}

// bits -> float in [0,1): (bits>>9)|0x3F800000 bitcast - 1.0 (JAX _uniform)
__device__ __forceinline__ float bits_to_f01(uint32_t b) {
  return __uint_as_float((b >> 9) | 0x3F800000u) - 1.0f;
}

// erfinv-lite: z such that noise = sqrt(2)*value*z. Branchless.
// Central: Giles poly truncated to 5 terms (|err| ~1e-3 over w<5).
// Tail (w>=5, 0.34% of lanes): z/x ~ 1.00167406*sqrt(w) - 0.17204536
// (2-term Giles tail, |err| <= 0.013 -> 9e-4 in output; budget is 0.108).
__device__ __forceinline__ float zlite(uint32_t bits) {
  float f = __uint_as_float((bits >> 9) | 0x3F800000u) - 1.0f;
  const float lo = __uint_as_float(0xBF7FFFFFu);  // nextafter(-1.f, 0.f)
  float x = fmaxf(lo, fmaf(f, 2.0f, lo));
  float w = -__logf(fmaf(-x, x, 1.0f));           // v_log + mul (neg folds)
  float t = w - 2.5f;
  float p = 0.00021858087f;
  p = fmaf(p, t, -0.00125372503f);
  p = fmaf(p, t, -0.00417768164f);
  p = fmaf(p, t, 0.246640727f);
  p = fmaf(p, t, 1.50140941f);
  float pt = fmaf(1.00167406f, __builtin_amdgcn_sqrtf(w), -0.17204536f);
  p = (w < 5.0f) ? p : pt;
  return p * x;
}

// order-preserving float<->uint encode for atomicMin on floats (incl. negatives)
__device__ __forceinline__ unsigned encf(float f) {
  unsigned u = __float_as_uint(f);
  return (u & 0x80000000u) ? ~u : (u | 0x80000000u);
}
__device__ __forceinline__ float decf(unsigned u) {
  unsigned b = (u & 0x80000000u) ? (u & 0x7FFFFFFFu) : ~u;
  return __uint_as_float(b);
}

// ---------------- prep: argmax over 80 class channels + per-tensor min -----
// 2 threads per pixel (40 channels each), shfl-merge; block=64, grid=1050.
__global__ __launch_bounds__(64) void prep_all(
    const float* __restrict__ x0, const float* __restrict__ x1,
    const float* __restrict__ x2, int* __restrict__ m0, int* __restrict__ m1,
    int* __restrict__ m2, unsigned* __restrict__ mins) {
  unsigned bid = blockIdx.x;
  const float* x; int* midx; unsigned* mE; unsigned N; unsigned lb;
  if (bid < 800u)       { x = x0; midx = m0; mE = mins;     N = 25600u; lb = bid; }
  else if (bid < 1000u) { x = x1; midx = m1; mE = mins + 1; N = 6400u;  lb = bid - 800u; }
  else                  { x = x2; midx = m2; mE = mins + 2; N = 1600u;  lb = bid - 1000u; }
  unsigned p = lb * 32u + (threadIdx.x >> 1);
  unsigned h = threadIdx.x & 1u;           // half: channels 40h .. 40h+39
  const float* pp = x + (5u + 40u * h) * N + p;
  float best = -INFINITY, mn = INFINITY;
  int bi = 0;
#pragma unroll
  for (int k = 0; k < 40; ++k) {
    float v = pp[(unsigned)k * N];
    if (v > best) { best = v; bi = (int)(40u * h) + k; }  // strict '>': first max
    mn = fminf(mn, v);
  }
  // merge the two halves of this pixel (lanes 2i, 2i+1)
  float ob = __shfl_xor(best, 1, 64);
  int obi = __shfl_xor(bi, 1, 64);
  float omn = __shfl_xor(mn, 1, 64);
  float bE = (h == 0u) ? best : ob;  int iE = (h == 0u) ? bi : obi;
  float bO = (h == 0u) ? ob : best;  int iO = (h == 0u) ? obi : bi;
  int mbi = (bO > bE) ? iO : iE;     // ties -> lower-k half (first max)
  mn = fminf(mn, omn);
  if (h == 0u) midx[p] = mbi;
  unsigned u = encf(mn);
  for (int off = 32; off > 0; off >>= 1) {
    unsigned o = __shfl_down(u, (unsigned)off, 64);
    u = (o < u) ? o : u;
  }
  if (threadIdx.x == 0u) atomicMin(mE, u);
}

// ---------------- fused main: scatter-replace (batch 0) + gaussian noise ----
struct TP {
  const float* x;
  float* out;
  const int* midx;
  uint32_t uk0, uk1, nk0, nk1;
  unsigned k;        // N = 25 << k
  unsigned N;
  unsigned tot;      // 680 * N
  unsigned blk_end;  // exclusive prefix sum of block counts
};

__global__ __launch_bounds__(256, 4) void main_all(
    TP p0, TP p1, TP p2, const unsigned* __restrict__ mins,
    const float* __restrict__ valuep) {
  unsigned bid = blockIdx.x;
  TP P; unsigned t;
  if (bid < p0.blk_end)      { P = p0; t = 0u; }
  else if (bid < p1.blk_end) { P = p1; t = 1u; bid -= p0.blk_end; }
  else                       { P = p2; t = 2u; bid -= p1.blk_end; }

  unsigned i0 = (bid * 256u + threadIdx.x) * 8u;   // 8 elements per thread
  if (i0 >= P.tot) return;

  // bc = i0 / N via (i0 >> k) / 25 (magic); b,c from bc < 680
  unsigned bc = __umulhi(i0 >> P.k, 0x51EB851Fu) >> 3;
  unsigned n0 = i0 - bc * P.N;         // 8 consecutive n, same (b,c)
  unsigned b = (bc * 772u) >> 16;      // exact for bc < 680
  unsigned c = bc - b * 85u;

  float4 va = *reinterpret_cast<const float4*>(P.x + i0);
  float4 vb = *reinterpret_cast<const float4*>(P.x + i0 + 4);
  float value = *valuep;
  float sv = value * 1.41421356237309515f;
  float vv[8] = {va.x, va.y, va.z, va.w, vb.x, vb.y, vb.z, vb.w};

  // ---- noise bits: 8 independent threefry chains, lockstep-4 x2 ----
  unsigned jb = (b * P.N + n0) * 85u + c;   // noise array [B,N,C] flat index
  uint32_t jn0[4] = {jb, jb + 85u, jb + 170u, jb + 255u};
  uint32_t jn1[4] = {jb + 340u, jb + 425u, jb + 510u, jb + 595u};
  uint32_t nb[8];
  tf4(P.nk0, P.nk1, jn0, nb);
  tf4(P.nk0, P.nk1, jn1, nb + 4);

  float nz[8];
#pragma unroll
  for (int q = 0; q < 8; ++q) nz[q] = zlite(nb[q]);

  // ---- class scatter-replace (batch 0, channels 5..84) ----
  if (b == 0u && c >= 5u) {
    unsigned kk = c - 5u;
    float clsmin = decf(mins[t]);
    int4 ma = *reinterpret_cast<const int4*>(P.midx + n0);
    int4 mb4 = *reinterpret_cast<const int4*>(P.midx + n0 + 4);
    int mm[8] = {ma.x, ma.y, ma.z, ma.w, mb4.x, mb4.y, mb4.z, mb4.w};
    unsigned ju = n0 * 80u + kk;              // uniform array [N,80]
    uint32_t ju0[4] = {ju, ju + 80u, ju + 160u, ju + 240u};
    uint32_t ju1[4] = {ju + 320u, ju + 400u, ju + 480u, ju + 560u};
    uint32_t ub[8];
    tf4(P.uk0, P.uk1, ju0, ub);
    tf4(P.uk0, P.uk1, ju1, ub + 4);
#pragma unroll
    for (int q = 0; q < 8; ++q) {
      if ((unsigned)mm[q] != kk) vv[q] = bits_to_f01(ub[q]) * clsmin;
    }
  }

#pragma unroll
  for (int q = 0; q < 8; ++q) vv[q] = fmaf(nz[q], sv, vv[q]);
  *reinterpret_cast<float4*>(P.out + i0) = make_float4(vv[0], vv[1], vv[2], vv[3]);
  *reinterpret_cast<float4*>(P.out + i0 + 4) = make_float4(vv[4], vv[5], vv[6], vv[7]);
}

extern "C" void kernel_launch(void* const* d_in, const int* in_sizes, int n_in,
                              void* d_out, int out_size, void* d_ws, size_t ws_size,
                              hipStream_t stream) {
  const float* xs[3] = {(const float*)d_in[0], (const float*)d_in[1], (const float*)d_in[2]};
  const float* valuep = (const float*)d_in[3];
  float* out = (float*)d_out;

  const unsigned Ns[3] = {25600u, 6400u, 1600u};
  const unsigned ks[3] = {10u, 8u, 6u};   // N = 25 << k

  // workspace: midx0 | midx1 | midx2 | mins[3]
  int* midx[3];
  midx[0] = (int*)d_ws;
  midx[1] = midx[0] + Ns[0];
  midx[2] = midx[1] + Ns[1];
  unsigned* mins = (unsigned*)(midx[2] + Ns[2]);
  hipMemsetAsync(mins, 0xFF, 3 * sizeof(unsigned), stream);

  // Host-side key derivation (partitionable threefry):
  //   base = key(42) = (0,42); key_i = threefry(base,(0,i));
  //   split(key_i) -> k1 = threefry(key_i,(0,0)) [uniform], k2 = threefry(key_i,(0,1)) [normal]
  TP p[3];
  unsigned blk_acc = 0;
  float* outp = out;
  for (int i = 0; i < 3; ++i) {
    uint32_t f0, f1;
    tf2x32(0u, 42u, 0u, (uint32_t)i, f0, f1);
    tf2x32(f0, f1, 0u, 0u, p[i].uk0, p[i].uk1);
    tf2x32(f0, f1, 0u, 1u, p[i].nk0, p[i].nk1);
    p[i].x = xs[i];
    p[i].out = outp;
    p[i].midx = midx[i];
    p[i].k = ks[i];
    p[i].N = Ns[i];
    p[i].tot = 680u * Ns[i];
    blk_acc += (p[i].tot / 8u + 255u) / 256u;
    p[i].blk_end = blk_acc;
    outp += (size_t)680 * Ns[i];
  }

  prep_all<<<1050, 64, 0, stream>>>(xs[0], xs[1], xs[2], midx[0], midx[1], midx[2], mins);
  main_all<<<blk_acc, 256, 0, stream>>>(p[0], p[1], p[2], mins, valuep);
}

// Round 5
// 79.256 us; speedup vs baseline: 1.0377x; 1.0377x over previous
//
#include <hip/hip_runtime.h>
#include <stdint.h>

// rotate-left via v_alignbit_b32 (guaranteed 1 instruction)
__device__ __forceinline__ uint32_t rotl(uint32_t v, int r) {
  return __builtin_amdgcn_alignbit(v, v, (uint32_t)(32 - r));
}

// ---------------- Threefry-2x32, 20 rounds (exactly JAX's) ----------------
__host__ __device__ inline void tf2x32(uint32_t k0, uint32_t k1,
                                       uint32_t x0, uint32_t x1,
                                       uint32_t& o0, uint32_t& o1) {
  uint32_t k2 = k0 ^ k1 ^ 0x1BD11BDAu;
#define TFR(r) { x0 += x1; x1 = (x1 << (r)) | (x1 >> (32 - (r))); x1 ^= x0; }
  x0 += k0; x1 += k1;
  TFR(13) TFR(15) TFR(26) TFR(6)  x0 += k1; x1 += k2 + 1u;
  TFR(17) TFR(29) TFR(16) TFR(24) x0 += k2; x1 += k0 + 2u;
  TFR(13) TFR(15) TFR(26) TFR(6)  x0 += k0; x1 += k1 + 3u;
  TFR(17) TFR(29) TFR(16) TFR(24) x0 += k1; x1 += k2 + 4u;
  TFR(13) TFR(15) TFR(26) TFR(6)  x0 += k2; x1 += k0 + 5u;
#undef TFR
  o0 = x0; o1 = x1;
}

// 4-chain lockstep threefry, alignbit rotates; out = o0^o1 (JAX partitionable
// random_bits with counter (0, j[i])).
__device__ __forceinline__ void tf4(uint32_t k0, uint32_t k1,
                                    const uint32_t j[4], uint32_t out[4]) {
  uint32_t k2 = k0 ^ k1 ^ 0x1BD11BDAu;
  uint32_t a[4], b[4];
#pragma unroll
  for (int i = 0; i < 4; ++i) { a[i] = k0; b[i] = j[i] + k1; }
#define RND(r)                                                         \
  _Pragma("unroll") for (int i = 0; i < 4; ++i) {                      \
    a[i] += b[i];                                                      \
    b[i] = rotl(b[i], (r)) ^ a[i];                                     \
  }
#define INJ(ka, kb, n)                                                 \
  _Pragma("unroll") for (int i = 0; i < 4; ++i) {                      \
    a[i] += (ka); b[i] += (kb) + (n);                                  \
  }
  RND(13) RND(15) RND(26) RND(6)  INJ(k1, k2, 1u)
  RND(17) RND(29) RND(16) RND(24) INJ(k2, k0, 2u)
  RND(13) RND(15) RND(26) RND(6)  INJ(k0, k1, 3u)
  RND(17) RND(29) RND(16) RND(24) INJ(k1, k2, 4u)
  RND(13) RND(15) RND(26) RND(6)  INJ(k2, k0, 5u)
#undef RND
#undef INJ
#pragma unroll
  for (int i = 0; i < 4; ++i) out[i] = a[i] ^ b[i];
}

// bits -> float in [0,1): (bits>>9)|0x3F800000 bitcast - 1.0 (JAX _uniform)
__device__ __forceinline__ float bits_to_f01(uint32_t b) {
  return __uint_as_float((b >> 9) | 0x3F800000u) - 1.0f;
}

// z = erfinv-lite(u(bits)) so that noise = sqrt(2)*value*z.
// Works in log2 domain: L = log2(1-x^2), w = -ln2*L.
// Central (w<5): Giles poly truncated to 5 terms (|err|~1e-3).
// Tail (w in [5,16], 0.34% lanes): linear fit z/x ~ 0.16063*w + 1.32724
// (err +-0.063 in z -> 0.0045 in output; budget 0.108). Branchless.
__device__ __forceinline__ float zlite(uint32_t bits) {
  float g = __uint_as_float((bits >> 9) | 0x3F800000u);   // [1,2)
  float f = g - 1.0f;                                      // uniform [0,1)
  const float lo = __uint_as_float(0xBF7FFFFFu);  // nextafter(-1.f, 0.f)
  float x = fmaxf(lo, fmaf(f, 2.0f, lo));
  float L = __log2f(fmaf(-x, x, 1.0f));           // log2(1-x^2), <= 0
  float t = fmaf(L, -0.69314718f, -2.5f);         // w - 2.5
  float p = 0.00021858087f;
  p = fmaf(p, t, -0.00125372503f);
  p = fmaf(p, t, -0.00417768164f);
  p = fmaf(p, t, 0.246640727f);
  p = fmaf(p, t, 1.50140941f);
  float pt = fmaf(L, -0.1113356f, 1.327237f);     // tail, linear in w
  p = (L > -7.2134752f) ? p : pt;                 // w < 5 ? central : tail
  return p * x;
}

// order-preserving float<->uint encode for atomicMin on floats (incl. negatives)
__device__ __forceinline__ unsigned encf(float f) {
  unsigned u = __float_as_uint(f);
  return (u & 0x80000000u) ? ~u : (u | 0x80000000u);
}
__device__ __forceinline__ float decf(unsigned u) {
  unsigned b = (u & 0x80000000u) ? (u & 0x7FFFFFFFu) : ~u;
  return __uint_as_float(b);
}

// ---------------- prep: argmax over 80 class channels + per-tensor min -----
// 2 threads per pixel (40 channels each), shfl-merge; block=256, grid=263.
__global__ __launch_bounds__(256) void prep_all(
    const float* __restrict__ x0, const float* __restrict__ x1,
    const float* __restrict__ x2, int* __restrict__ m0, int* __restrict__ m1,
    int* __restrict__ m2, unsigned* __restrict__ mins) {
  unsigned bid = blockIdx.x;
  const float* x; int* midx; unsigned* mE; unsigned N; unsigned lb;
  if (bid < 200u)      { x = x0; midx = m0; mE = mins;     N = 25600u; lb = bid; }
  else if (bid < 250u) { x = x1; midx = m1; mE = mins + 1; N = 6400u;  lb = bid - 200u; }
  else                 { x = x2; midx = m2; mE = mins + 2; N = 1600u;  lb = bid - 250u; }
  unsigned p = lb * 128u + (threadIdx.x >> 1);
  unsigned h = threadIdx.x & 1u;           // half: channels 40h .. 40h+39
  float best = -INFINITY, mn = INFINITY;
  int bi = 0;
  if (p < N) {
    const float* pp = x + (5u + 40u * h) * N + p;
#pragma unroll 8
    for (int k = 0; k < 40; ++k) {
      float v = pp[(unsigned)k * N];
      if (v > best) { best = v; bi = (int)(40u * h) + k; }  // strict '>': first max
      mn = fminf(mn, v);
    }
  }
  // merge the two halves of this pixel (lanes 2i, 2i+1)
  float ob = __shfl_xor(best, 1, 64);
  int obi = __shfl_xor(bi, 1, 64);
  float omn = __shfl_xor(mn, 1, 64);
  float bE = (h == 0u) ? best : ob;  int iE = (h == 0u) ? bi : obi;
  float bO = (h == 0u) ? ob : best;  int iO = (h == 0u) ? obi : bi;
  int mbi = (bO > bE) ? iO : iE;     // ties -> lower-k half (first max)
  mn = fminf(mn, omn);
  if (h == 0u && p < N) midx[p] = mbi;
  unsigned u = encf(mn);
  for (int off = 32; off > 0; off >>= 1) {
    unsigned o = __shfl_down(u, (unsigned)off, 64);
    u = (o < u) ? o : u;
  }
  if ((threadIdx.x & 63u) == 0u) atomicMin(mE, u);
}

// ---------------- fused main: scatter-replace (batch 0) + gaussian noise ----
struct TP {
  const float* x;
  float* out;
  const int* midx;
  uint32_t uk0, uk1, nk0, nk1;
  unsigned k;        // N = 25 << k
  unsigned N;
  unsigned tot;      // 680 * N
  unsigned blk_end;  // exclusive prefix sum of block counts
};

__global__ __launch_bounds__(256) void main_all(
    TP p0, TP p1, TP p2, const unsigned* __restrict__ mins,
    const float* __restrict__ valuep) {
  unsigned bid = blockIdx.x;
  TP P; unsigned t;
  if (bid < p0.blk_end)      { P = p0; t = 0u; }
  else if (bid < p1.blk_end) { P = p1; t = 1u; bid -= p0.blk_end; }
  else                       { P = p2; t = 2u; bid -= p1.blk_end; }

  unsigned i0 = (bid * 256u + threadIdx.x) * 8u;   // 8 elements per thread
  if (i0 >= P.tot) return;

  // bc = i0 / N via (i0 >> k) / 25 (magic); b,c from bc < 680
  unsigned bc = __umulhi(i0 >> P.k, 0x51EB851Fu) >> 3;
  unsigned n0 = i0 - bc * P.N;         // 8 consecutive n, same (b,c)
  unsigned b = (bc * 772u) >> 16;      // exact for bc < 680
  unsigned c = bc - b * 85u;

  float4 va = *reinterpret_cast<const float4*>(P.x + i0);
  float4 vb = *reinterpret_cast<const float4*>(P.x + i0 + 4);
  float value = *valuep;
  float sv = value * 1.41421356237309515f;
  float vv[8] = {va.x, va.y, va.z, va.w, vb.x, vb.y, vb.z, vb.w};

  // ---- noise bits: 8 independent threefry chains, lockstep-4 x2 ----
  unsigned jb = (b * P.N + n0) * 85u + c;   // noise array [B,N,C] flat index
  uint32_t jn0[4] = {jb, jb + 85u, jb + 170u, jb + 255u};
  uint32_t jn1[4] = {jb + 340u, jb + 425u, jb + 510u, jb + 595u};
  uint32_t nb[8];
  tf4(P.nk0, P.nk1, jn0, nb);
  tf4(P.nk0, P.nk1, jn1, nb + 4);

  float nz[8];
#pragma unroll
  for (int q = 0; q < 8; ++q) nz[q] = zlite(nb[q]);

  // ---- class scatter-replace (batch 0, channels 5..84) ----
  if (b == 0u && c >= 5u) {
    unsigned kk = c - 5u;
    float clsmin = decf(mins[t]);
    int4 ma = *reinterpret_cast<const int4*>(P.midx + n0);
    int4 mb4 = *reinterpret_cast<const int4*>(P.midx + n0 + 4);
    int mm[8] = {ma.x, ma.y, ma.z, ma.w, mb4.x, mb4.y, mb4.z, mb4.w};
    unsigned ju = n0 * 80u + kk;              // uniform array [N,80]
    uint32_t ju0[4] = {ju, ju + 80u, ju + 160u, ju + 240u};
    uint32_t ju1[4] = {ju + 320u, ju + 400u, ju + 480u, ju + 560u};
    uint32_t ub[8];
    tf4(P.uk0, P.uk1, ju0, ub);
    tf4(P.uk0, P.uk1, ju1, ub + 4);
#pragma unroll
    for (int q = 0; q < 8; ++q) {
      if ((unsigned)mm[q] != kk) vv[q] = bits_to_f01(ub[q]) * clsmin;
    }
  }

#pragma unroll
  for (int q = 0; q < 8; ++q) vv[q] = fmaf(nz[q], sv, vv[q]);
  *reinterpret_cast<float4*>(P.out + i0) = make_float4(vv[0], vv[1], vv[2], vv[3]);
  *reinterpret_cast<float4*>(P.out + i0 + 4) = make_float4(vv[4], vv[5], vv[6], vv[7]);
}

extern "C" void kernel_launch(void* const* d_in, const int* in_sizes, int n_in,
                              void* d_out, int out_size, void* d_ws, size_t ws_size,
                              hipStream_t stream) {
  const float* xs[3] = {(const float*)d_in[0], (const float*)d_in[1], (const float*)d_in[2]};
  const float* valuep = (const float*)d_in[3];
  float* out = (float*)d_out;

  const unsigned Ns[3] = {25600u, 6400u, 1600u};
  const unsigned ks[3] = {10u, 8u, 6u};   // N = 25 << k

  // workspace: midx0 | midx1 | midx2 | mins[3]
  int* midx[3];
  midx[0] = (int*)d_ws;
  midx[1] = midx[0] + Ns[0];
  midx[2] = midx[1] + Ns[1];
  unsigned* mins = (unsigned*)(midx[2] + Ns[2]);
  hipMemsetAsync(mins, 0xFF, 3 * sizeof(unsigned), stream);

  // Host-side key derivation (partitionable threefry):
  //   base = key(42) = (0,42); key_i = threefry(base,(0,i));
  //   split(key_i) -> k1 = threefry(key_i,(0,0)) [uniform], k2 = threefry(key_i,(0,1)) [normal]
  TP p[3];
  unsigned blk_acc = 0;
  float* outp = out;
  for (int i = 0; i < 3; ++i) {
    uint32_t f0, f1;
    tf2x32(0u, 42u, 0u, (uint32_t)i, f0, f1);
    tf2x32(f0, f1, 0u, 0u, p[i].uk0, p[i].uk1);
    tf2x32(f0, f1, 0u, 1u, p[i].nk0, p[i].nk1);
    p[i].x = xs[i];
    p[i].out = outp;
    p[i].midx = midx[i];
    p[i].k = ks[i];
    p[i].N = Ns[i];
    p[i].tot = 680u * Ns[i];
    blk_acc += (p[i].tot / 8u + 255u) / 256u;
    p[i].blk_end = blk_acc;
    outp += (size_t)680 * Ns[i];
  }

  prep_all<<<263, 256, 0, stream>>>(xs[0], xs[1], xs[2], midx[0], midx[1], midx[2], mins);
  main_all<<<blk_acc, 256, 0, stream>>>(p[0], p[1], p[2], mins, valuep);
}